// Round 2
// baseline (480.439 us; speedup 1.0000x reference)
//
#include <hip/hip_runtime.h>
#include <hip/hip_bf16.h>

typedef __bf16 bf16x8 __attribute__((ext_vector_type(8)));
typedef float f32x4 __attribute__((ext_vector_type(4)));

#define DIM 128
#define LOG_2PI 1.8378770664093453f

__device__ __forceinline__ unsigned short f2bf(float f) {
    unsigned int u = __float_as_uint(f);
    u += 0x7FFFu + ((u >> 16) & 1u);
    return (unsigned short)(u >> 16);
}

// ---------------------------------------------------------------------------
// Setup kernel (1 block, 256 threads):
//   sig = sigma + eps (LDS), Cholesky sig = L L^T (lower, in place),
//   logdet = 2*sum(log Lii), U = L^{-1} (lower, in place),
//   write B[d][e] = U[e][d] as bf16 in MFMA-fragment order:
//     ws_B[(d>>3)*1024 + e*8 + (d&7)]
//   ws_scal[0] = 0.5*(D*log(2pi) + logdet)
// ---------------------------------------------------------------------------
__global__ __launch_bounds__(256) void gm_setup(
    const float* __restrict__ sigma, const float* __restrict__ eps,
    __hip_bfloat16* __restrict__ wsB, float* __restrict__ wsScal)
{
    __shared__ float A[DIM][DIM + 1];
    __shared__ float sc0;
    const int tid = threadIdx.x;

    for (int idx = tid; idx < DIM * DIM; idx += 256) {
        const int r = idx >> 7, c = idx & 127;
        A[r][c] = sigma[idx] + eps[idx];
    }
    __syncthreads();

    // ---- Cholesky (lower), right-looking ----
    for (int k = 0; k < DIM; ++k) {
        if (tid == 0) {
            const float dv = sqrtf(A[k][k]);
            A[k][k] = dv;
            sc0 = 1.0f / dv;
        }
        __syncthreads();
        const float dinv = sc0;
        if (tid > k && tid < DIM) A[tid][k] *= dinv;
        __syncthreads();
        if (tid > k && tid < DIM) {
            const int i = tid;
            const float f = A[i][k];
            for (int j = k + 1; j <= i; ++j) A[i][j] -= f * A[j][k];
        }
        __syncthreads();
    }

    // ---- log_den ----
    if (tid == 0) {
        float s = 0.0f;
        for (int i = 0; i < DIM; ++i) s += logf(A[i][i]);
        wsScal[0] = 0.5f * ((float)DIM * LOG_2PI + 2.0f * s);
    }

    // ---- zero strict upper triangle (needed by trinv's uniform k-sum) ----
    for (int idx = tid; idx < DIM * DIM; idx += 256) {
        const int r = idx >> 7, c = idx & 127;
        if (c > r) A[r][c] = 0.0f;
    }
    __syncthreads();

    // ---- triangular inverse U = L^{-1} (lower), in place, rows ascending ----
    // row i: U[i][j] = -(1/L[i][i]) * sum_{k<i} L[i][k]*U[k][j]   (j < i)
    //        U[i][i] = 1/L[i][i]
    // 32 threads, 4 columns each; upper-zeros make the k-sum uniform over j.
    for (int i = 0; i < DIM; ++i) {
        if (tid < 32) {
            const int j0 = tid * 4;
            float a0 = 0.f, a1 = 0.f, a2 = 0.f, a3 = 0.f;
            for (int k = 0; k < i; ++k) {
                const float lik = A[i][k];
                a0 += lik * A[k][j0 + 0];
                a1 += lik * A[k][j0 + 1];
                a2 += lik * A[k][j0 + 2];
                a3 += lik * A[k][j0 + 3];
            }
            const float nuii = -1.0f / A[i][i];
            if (j0 + 0 < i) A[i][j0 + 0] = nuii * a0;
            if (j0 + 1 < i) A[i][j0 + 1] = nuii * a1;
            if (j0 + 2 < i) A[i][j0 + 2] = nuii * a2;
            if (j0 + 3 < i) A[i][j0 + 3] = nuii * a3;
            if (i >= j0 && i < j0 + 4) A[i][i] = -nuii;  // 1/L[i][i]
        }
        __syncthreads();
    }

    // ---- write B in fragment order: B[k=d][col=e] = U[e][d] ----
    for (int idx = tid; idx < DIM * DIM; idx += 256) {
        const int e = idx >> 7, d = idx & 127;
        const float v = A[e][d];  // zero when d > e
        wsB[(d >> 3) * 1024 + e * 8 + (d & 7)] = __float2bfloat16(v);
    }
}

// ---------------------------------------------------------------------------
// Main kernel: persistent blocks, 64-row tiles.
//   Y[64,128] = (X_tile - mu)_bf16 @ B ;  quad = rowsum(Y^2)
//   out = 0.5*quad + log_den
// 4 waves x 16 rows each; mfma_f32_16x16x32_bf16; A-tile XOR-swizzled in LDS.
// ---------------------------------------------------------------------------
__global__ __launch_bounds__(256) void gm_main(
    const float* __restrict__ X, const float* __restrict__ mu,
    const __hip_bfloat16* __restrict__ wsB, const float* __restrict__ wsScal,
    float* __restrict__ out, int ntiles)
{
    __shared__ __hip_bfloat16 sB[16 * 1024];  // 32KB, fragment-ordered
    __shared__ unsigned short sA[64 * 128];   // 16KB, swizzled bf16 diff tile
    __shared__ float s_mu[DIM];

    const int tid  = threadIdx.x;
    const int lane = tid & 63;
    const int wave = tid >> 6;
    const int l15  = lane & 15;
    const int l4   = lane >> 4;

    {   // stage B (tile-invariant) and mu once
        const float4* bg = reinterpret_cast<const float4*>(wsB);
        float4* bs = reinterpret_cast<float4*>(sB);
#pragma unroll
        for (int i = 0; i < 8; ++i) bs[tid + i * 256] = bg[tid + i * 256];
        if (tid < DIM) s_mu[tid] = mu[tid];
    }
    const float logden = wsScal[0];
    __syncthreads();  // s_mu/sB visible to all waves before first tile staging

    for (int t = blockIdx.x; t < ntiles; t += gridDim.x) {
        // ---- stage 64x128 diff tile -> bf16, XOR-swizzled ----
        const float4* xg = reinterpret_cast<const float4*>(X + (size_t)t * (64 * DIM));
#pragma unroll
        for (int i = 0; i < 8; ++i) {
            const int idx = tid + i * 256;
            const int r  = idx >> 5;   // row 0..63
            const int c4 = idx & 31;   // float4 col block
            float4 v = xg[idx];
            v.x -= s_mu[c4 * 4 + 0];
            v.y -= s_mu[c4 * 4 + 1];
            v.z -= s_mu[c4 * 4 + 2];
            v.w -= s_mu[c4 * 4 + 3];
            ushort4 b;
            b.x = f2bf(v.x); b.y = f2bf(v.y); b.z = f2bf(v.z); b.w = f2bf(v.w);
            char* p = (char*)sA + r * 256 + ((((c4 >> 1) ^ (r & 7)) << 4) | ((c4 & 1) << 3));
            *reinterpret_cast<ushort4*>(p) = b;
        }
        __syncthreads();

        // ---- MFMA: Y = diff @ B, accumulate quad ----
        f32x4 acc[8];
#pragma unroll
        for (int c = 0; c < 8; ++c) { acc[c][0] = 0.f; acc[c][1] = 0.f; acc[c][2] = 0.f; acc[c][3] = 0.f; }

        const int arow = wave * 16 + l15;
        const char* aBase = (const char*)sA + arow * 256;
#pragma unroll
        for (int kk = 0; kk < 4; ++kk) {
            const int kchunk = kk * 4 + l4;  // 0..15
            bf16x8 af = *reinterpret_cast<const bf16x8*>(aBase + ((kchunk ^ (arow & 7)) << 4));
            const __hip_bfloat16* bbase = sB + kchunk * 1024 + l15 * 8;
#pragma unroll
            for (int c = 0; c < 8; ++c) {
                bf16x8 bf = *reinterpret_cast<const bf16x8*>(bbase + c * 128);
                acc[c] = __builtin_amdgcn_mfma_f32_16x16x32_bf16(af, bf, acc[c], 0, 0, 0);
            }
        }

        // ---- quad = rowsum(Y^2): per-lane partials + butterfly over 16 lanes ----
        float q0 = 0.f, q1 = 0.f, q2 = 0.f, q3 = 0.f;
#pragma unroll
        for (int c = 0; c < 8; ++c) {
            q0 += acc[c][0] * acc[c][0];
            q1 += acc[c][1] * acc[c][1];
            q2 += acc[c][2] * acc[c][2];
            q3 += acc[c][3] * acc[c][3];
        }
#pragma unroll
        for (int off = 1; off < 16; off <<= 1) {
            q0 += __shfl_xor(q0, off, 64);
            q1 += __shfl_xor(q1, off, 64);
            q2 += __shfl_xor(q2, off, 64);
            q3 += __shfl_xor(q3, off, 64);
        }
        if (l15 == 0) {
            float4 o;
            o.x = 0.5f * q0 + logden;
            o.y = 0.5f * q1 + logden;
            o.z = 0.5f * q2 + logden;
            o.w = 0.5f * q3 + logden;
            *reinterpret_cast<float4*>(out + (size_t)t * 64 + wave * 16 + l4 * 4) = o;
        }
        __syncthreads();  // protect sA before next tile's staging
    }
}

extern "C" void kernel_launch(void* const* d_in, const int* in_sizes, int n_in,
                              void* d_out, int out_size, void* d_ws, size_t ws_size,
                              hipStream_t stream) {
    const float* X     = (const float*)d_in[0];
    const float* mu    = (const float*)d_in[1];
    const float* sigma = (const float*)d_in[2];
    const float* eps   = (const float*)d_in[3];
    float* out = (float*)d_out;

    __hip_bfloat16* wsB = (__hip_bfloat16*)d_ws;
    float* wsScal = (float*)((char*)d_ws + 32768);

    const int N = in_sizes[0] / DIM;
    const int ntiles = N / 64;

    hipLaunchKernelGGL(gm_setup, dim3(1), dim3(256), 0, stream, sigma, eps, wsB, wsScal);

    const int grid = ntiles < 768 ? ntiles : 768;
    hipLaunchKernelGGL(gm_main, dim3(grid), dim3(256), 0, stream,
                       X, mu, wsB, wsScal, out, ntiles);
}

// Round 3
// 301.900 us; speedup vs baseline: 1.5914x; 1.5914x over previous
//
#include <hip/hip_runtime.h>
#include <hip/hip_bf16.h>

typedef __bf16 bf16x8 __attribute__((ext_vector_type(8)));
typedef float f32x4 __attribute__((ext_vector_type(4)));

#define DIM 128
#define LOG_2PI 1.8378770664093453f

__device__ __forceinline__ unsigned short f2bf(float f) {
    unsigned int u = __float_as_uint(f);
    u += 0x7FFFu + ((u >> 16) & 1u);
    return (unsigned short)(u >> 16);
}

// ---------------------------------------------------------------------------
// Setup kernel (1 block, 1024 threads):
//   A = sigma + eps (LDS, lower triangle is the live data)
//   Symmetric elimination with DEFERRED scaling (1 barrier/step):
//     step k:  A[i][j] -= A[i][k]*A[j][k]/d_k   (k<j<=i),  d_k = A[k][k]
//   -> pivots d_k on diagonal (logdet = sum log d_k)
//   -> Cholesky factor Lc[r][c] = A[r][c]*rsqrt(d_c)  (c<=r)
//   U = Lc^{-1} via 128 independent column forward-substitutions
//     (thread j owns column j; U[i][j] stored at A[j][i])
//   Emit B[d][e] = U[e][d] as bf16 in MFMA fragment order:
//     wsB[(d>>3)*1024 + e*8 + (d&7)]
//   wsScal[0] = 0.5*(D*log(2pi) + logdet)
// ---------------------------------------------------------------------------
__global__ __launch_bounds__(1024) void gm_setup(
    const float* __restrict__ sigma, const float* __restrict__ eps,
    __hip_bfloat16* __restrict__ wsB, float* __restrict__ wsScal)
{
    __shared__ float A[DIM][DIM + 1];    // working matrix, then U columns in rows
    __shared__ float Lc[DIM][DIM + 1];   // scaled Cholesky factor
    __shared__ float rd[DIM];            // rsqrt(d_k) == 1/Lc[k][k]
    __shared__ float red[DIM];           // log(d_k)

    const int tid = threadIdx.x;         // 0..1023
    const int i = tid & 127;             // row (lanes in a wave = consecutive rows)
    const int g = tid >> 7;              // column group 0..7

    // ---- load sig = sigma + eps ----
    for (int idx = tid; idx < DIM * DIM; idx += 1024) {
        A[idx >> 7][idx & 127] = sigma[idx] + eps[idx];
    }
    __syncthreads();

    // ---- symmetric elimination, deferred scaling: ONE barrier per step ----
    // Reads this step: column k (A[.][k]) and pivot A[k][k] — all finalized at
    // step k-1. Writes: A[i][j], k<j<=i, partitioned by (i, j mod 8). No race.
    for (int k = 0; k < DIM; ++k) {
        const float rinv = 1.0f / A[k][k];
        if (i > k) {
            const float f = A[i][k] * rinv;
            for (int j = k + 1 + g; j <= i; j += 8)
                A[i][j] -= f * A[j][k];
        }
        __syncthreads();
    }

    // ---- pivot-derived scalars (parallel) ----
    if (tid < DIM) {
        const float d = A[tid][tid];
        rd[tid]  = rsqrtf(d);
        red[tid] = logf(d);
    }
    __syncthreads();

    // ---- build Lc (zero upper) ----
    for (int idx = tid; idx < DIM * DIM; idx += 1024) {
        const int r = idx >> 7, c = idx & 127;
        Lc[r][c] = (c <= r) ? A[r][c] * rd[c] : 0.0f;
    }
    __syncthreads();

    // ---- logdet sum on an FS-idle thread ----
    if (tid == 1023) {
        float s = 0.0f;
        for (int t = 0; t < DIM; ++t) s += red[t];
        wsScal[0] = 0.5f * ((float)DIM * LOG_2PI + s);
    }

    // ---- U = Lc^{-1}: column j per thread, forward substitution ----
    // U[i2][j] stored at A[j][i2] (row j of A reused as column-j storage).
    // Reads: Lc (frozen), own row of A only. No cross-thread hazard.
    if (tid < DIM) {
        const int j = tid;
        for (int i2 = j; i2 < DIM; ++i2) {
            float s = (i2 == j) ? 1.0f : 0.0f;
            for (int k = j; k < i2; ++k)
                s -= Lc[i2][k] * A[j][k];
            A[j][i2] = s * rd[i2];
        }
    }
    __syncthreads();

    // ---- write B in fragment order: B[d][e] = U[e][d] = A[d][e] (d<=e) ----
    for (int idx = tid; idx < DIM * DIM; idx += 1024) {
        const int e = idx >> 7, d = idx & 127;
        const float v = (d <= e) ? A[d][e] : 0.0f;
        wsB[(d >> 3) * 1024 + e * 8 + (d & 7)] = __float2bfloat16(v);
    }
}

// ---------------------------------------------------------------------------
// Main kernel: persistent blocks, 64-row tiles.  (UNCHANGED — verified)
//   Y[64,128] = (X_tile - mu)_bf16 @ B ;  quad = rowsum(Y^2)
//   out = 0.5*quad + log_den
// 4 waves x 16 rows each; mfma_f32_16x16x32_bf16; A-tile XOR-swizzled in LDS.
// ---------------------------------------------------------------------------
__global__ __launch_bounds__(256) void gm_main(
    const float* __restrict__ X, const float* __restrict__ mu,
    const __hip_bfloat16* __restrict__ wsB, const float* __restrict__ wsScal,
    float* __restrict__ out, int ntiles)
{
    __shared__ __hip_bfloat16 sB[16 * 1024];  // 32KB, fragment-ordered
    __shared__ unsigned short sA[64 * 128];   // 16KB, swizzled bf16 diff tile
    __shared__ float s_mu[DIM];

    const int tid  = threadIdx.x;
    const int lane = tid & 63;
    const int wave = tid >> 6;
    const int l15  = lane & 15;
    const int l4   = lane >> 4;

    {   // stage B (tile-invariant) and mu once
        const float4* bg = reinterpret_cast<const float4*>(wsB);
        float4* bs = reinterpret_cast<float4*>(sB);
#pragma unroll
        for (int i = 0; i < 8; ++i) bs[tid + i * 256] = bg[tid + i * 256];
        if (tid < DIM) s_mu[tid] = mu[tid];
    }
    const float logden = wsScal[0];
    __syncthreads();  // s_mu/sB visible to all waves before first tile staging

    for (int t = blockIdx.x; t < ntiles; t += gridDim.x) {
        // ---- stage 64x128 diff tile -> bf16, XOR-swizzled ----
        const float4* xg = reinterpret_cast<const float4*>(X + (size_t)t * (64 * DIM));
#pragma unroll
        for (int i = 0; i < 8; ++i) {
            const int idx = tid + i * 256;
            const int r  = idx >> 5;   // row 0..63
            const int c4 = idx & 31;   // float4 col block
            float4 v = xg[idx];
            v.x -= s_mu[c4 * 4 + 0];
            v.y -= s_mu[c4 * 4 + 1];
            v.z -= s_mu[c4 * 4 + 2];
            v.w -= s_mu[c4 * 4 + 3];
            ushort4 b;
            b.x = f2bf(v.x); b.y = f2bf(v.y); b.z = f2bf(v.z); b.w = f2bf(v.w);
            char* p = (char*)sA + r * 256 + ((((c4 >> 1) ^ (r & 7)) << 4) | ((c4 & 1) << 3));
            *reinterpret_cast<ushort4*>(p) = b;
        }
        __syncthreads();

        // ---- MFMA: Y = diff @ B, accumulate quad ----
        f32x4 acc[8];
#pragma unroll
        for (int c = 0; c < 8; ++c) { acc[c][0] = 0.f; acc[c][1] = 0.f; acc[c][2] = 0.f; acc[c][3] = 0.f; }

        const int arow = wave * 16 + l15;
        const char* aBase = (const char*)sA + arow * 256;
#pragma unroll
        for (int kk = 0; kk < 4; ++kk) {
            const int kchunk = kk * 4 + l4;  // 0..15
            bf16x8 af = *reinterpret_cast<const bf16x8*>(aBase + ((kchunk ^ (arow & 7)) << 4));
            const __hip_bfloat16* bbase = sB + kchunk * 1024 + l15 * 8;
#pragma unroll
            for (int c = 0; c < 8; ++c) {
                bf16x8 bf = *reinterpret_cast<const bf16x8*>(bbase + c * 128);
                acc[c] = __builtin_amdgcn_mfma_f32_16x16x32_bf16(af, bf, acc[c], 0, 0, 0);
            }
        }

        // ---- quad = rowsum(Y^2): per-lane partials + butterfly over 16 lanes ----
        float q0 = 0.f, q1 = 0.f, q2 = 0.f, q3 = 0.f;
#pragma unroll
        for (int c = 0; c < 8; ++c) {
            q0 += acc[c][0] * acc[c][0];
            q1 += acc[c][1] * acc[c][1];
            q2 += acc[c][2] * acc[c][2];
            q3 += acc[c][3] * acc[c][3];
        }
#pragma unroll
        for (int off = 1; off < 16; off <<= 1) {
            q0 += __shfl_xor(q0, off, 64);
            q1 += __shfl_xor(q1, off, 64);
            q2 += __shfl_xor(q2, off, 64);
            q3 += __shfl_xor(q3, off, 64);
        }
        if (l15 == 0) {
            float4 o;
            o.x = 0.5f * q0 + logden;
            o.y = 0.5f * q1 + logden;
            o.z = 0.5f * q2 + logden;
            o.w = 0.5f * q3 + logden;
            *reinterpret_cast<float4*>(out + (size_t)t * 64 + wave * 16 + l4 * 4) = o;
        }
        __syncthreads();  // protect sA before next tile's staging
    }
}

extern "C" void kernel_launch(void* const* d_in, const int* in_sizes, int n_in,
                              void* d_out, int out_size, void* d_ws, size_t ws_size,
                              hipStream_t stream) {
    const float* X     = (const float*)d_in[0];
    const float* mu    = (const float*)d_in[1];
    const float* sigma = (const float*)d_in[2];
    const float* eps   = (const float*)d_in[3];
    float* out = (float*)d_out;

    __hip_bfloat16* wsB = (__hip_bfloat16*)d_ws;
    float* wsScal = (float*)((char*)d_ws + 32768);

    const int N = in_sizes[0] / DIM;
    const int ntiles = N / 64;

    hipLaunchKernelGGL(gm_setup, dim3(1), dim3(1024), 0, stream, sigma, eps, wsB, wsScal);

    const int grid = ntiles < 768 ? ntiles : 768;
    hipLaunchKernelGGL(gm_main, dim3(grid), dim3(256), 0, stream,
                       X, mu, wsB, wsScal, out, ntiles);
}

// Round 6
// 168.909 us; speedup vs baseline: 2.8444x; 1.7874x over previous
//
#include <hip/hip_runtime.h>
#include <hip/hip_bf16.h>

typedef __bf16 bf16x8 __attribute__((ext_vector_type(8)));
typedef float f32x4 __attribute__((ext_vector_type(4)));

#define DIM 128
#define LOG_2PI 1.8378770664093453f
#define NS_ITERS 9

__device__ __forceinline__ unsigned short f2bf(float f) {
    unsigned int u = __float_as_uint(f);
    u += 0x7FFFu + ((u >> 16) & 1u);
    return (unsigned short)(u >> 16);
}
__device__ __forceinline__ float bfu(unsigned short u) {
    return __uint_as_float((unsigned int)u << 16);
}
// fragment-order index: FO[(r>>3)*1024 + c*8 + (r&7)] = M[r][c]
__device__ __forceinline__ int foidx(int r, int c) {
    return ((r >> 3) << 10) + (c << 3) + (r & 7);
}

// acc += P^T * Q  (P,Q bf16 in fragment order; conflict-free ds_read_b128)
__device__ __forceinline__ void mm_acc(const unsigned short* __restrict__ Ps,
                                       const unsigned short* __restrict__ Qs,
                                       f32x4* acc, int tr, int tcb, int l15, int l4)
{
#pragma unroll
    for (int kk = 0; kk < 4; ++kk) {
        const int kc = kk * 4 + l4;
        const bf16x8 a = *reinterpret_cast<const bf16x8*>(Ps + (kc << 10) + ((tr * 16 + l15) << 3));
#pragma unroll
        for (int c = 0; c < 4; ++c) {
            const bf16x8 b = *reinterpret_cast<const bf16x8*>(Qs + (kc << 10) + (((tcb + c) * 16 + l15) << 3));
            acc[c] = __builtin_amdgcn_mfma_f32_16x16x32_bf16(a, b, acc[c], 0, 0, 0);
        }
    }
}

__device__ __forceinline__ void wb_hi(unsigned short* __restrict__ C, const f32x4* acc,
                                      int tr, int tcb, int l15, int l4)
{
#pragma unroll
    for (int c = 0; c < 4; ++c)
#pragma unroll
        for (int j = 0; j < 4; ++j)
            C[foidx(tr * 16 + l4 * 4 + j, (tcb + c) * 16 + l15)] = f2bf(acc[c][j]);
}

__device__ __forceinline__ void wb_hi_neg(unsigned short* __restrict__ C, const f32x4* acc,
                                          int tr, int tcb, int l15, int l4)
{
#pragma unroll
    for (int c = 0; c < 4; ++c)
#pragma unroll
        for (int j = 0; j < 4; ++j)
            C[foidx(tr * 16 + l4 * 4 + j, (tcb + c) * 16 + l15)] = f2bf(-acc[c][j]);
}

__device__ __forceinline__ void wb_split(unsigned short* __restrict__ Chi,
                                         unsigned short* __restrict__ Clo,
                                         const f32x4* acc, int tr, int tcb, int l15, int l4)
{
#pragma unroll
    for (int c = 0; c < 4; ++c)
#pragma unroll
        for (int j = 0; j < 4; ++j) {
            const float v = acc[c][j];
            const unsigned short hi = f2bf(v);
            const int f = foidx(tr * 16 + l4 * 4 + j, (tcb + c) * 16 + l15);
            Chi[f] = hi;
            Clo[f] = f2bf(v - bfu(hi));
        }
}

// ---------------------------------------------------------------------------
// Setup (1 block, 1024 threads = 16 waves, MFMA-based):
//   S = sigma+eps split bf16 hi/lo (B0,B1), fragment order
//   Newton-Schulz X <- 2X - X^T(S X), X0 = I/gershgorin(S), 9 iters (B2)
//   symmetrize X; split refinement W = X^T(2I - S X) -> B0(hi),B1(lo)
//   symmetrize W; wsB = W_hi
//   M = I - W -> B2,B3; logdet = sum_k tr(M^k)/k, k=1..24, Frobenius trick
//   wsScal[0] = 0.5*(D*log(2pi) + logdet)
// ---------------------------------------------------------------------------
__global__ __launch_bounds__(1024) void gm_setup(
    const float* __restrict__ sigma, const float* __restrict__ eps,
    unsigned short* __restrict__ wsB, float* __restrict__ wsScal)
{
    __shared__ __align__(16) unsigned short B0[16384];  // S_hi -> W_hi
    __shared__ __align__(16) unsigned short B1[16384];  // S_lo -> T/E_lo -> W_lo
    __shared__ __align__(16) unsigned short B2[16384];  // X -> M
    __shared__ __align__(16) unsigned short B3[16384];  // -T / E_hi -> P_j
    __shared__ float sred[DIM];
    __shared__ float sscal[1];

    const int tid  = threadIdx.x;
    const int lane = tid & 63;
    const int w    = tid >> 6;
    const int l15  = lane & 15;
    const int l4   = lane >> 4;
    const int tr   = w >> 1;          // output tile-row 0..7
    const int tcb  = (w & 1) * 4;     // output tile-col base 0 or 4

    // ---- load S = sigma + eps, split hi/lo, fragment order ----
    for (int idx = tid; idx < 16384; idx += 1024) {
        const int r = idx >> 7, c = idx & 127;
        const float s = sigma[idx] + eps[idx];
        const unsigned short hi = f2bf(s);
        const int f = foidx(r, c);
        B0[f] = hi;
        B1[f] = f2bf(s - bfu(hi));
    }
    __syncthreads();

    // ---- Gershgorin bound b >= lambda_max(S);  x0 = 1/b ----
    if (tid < DIM) {
        const int base = ((tid >> 3) << 10) + (tid & 7);
        float s = 0.f;
        for (int c = 0; c < DIM; ++c) s += fabsf(bfu(B0[base + (c << 3)]));
        sred[tid] = s;
    }
    __syncthreads();
    if (tid < 64) {
        float m = fmaxf(sred[tid], sred[tid + 64]);
#pragma unroll
        for (int off = 32; off; off >>= 1) m = fmaxf(m, __shfl_xor(m, off, 64));
        if (tid == 0) sscal[0] = 1.0f / (m * 1.0078125f);
    }
    __syncthreads();
    const float x0 = sscal[0];

    // ---- X0 = x0 * I ----
    for (int idx = tid; idx < 16384; idx += 1024) {
        const int r = idx >> 7, c = idx & 127;
        B2[foidx(r, c)] = (r == c) ? f2bf(x0) : (unsigned short)0;
    }
    __syncthreads();

    // ---- Newton-Schulz: X <- 2X + X^T(-T), T = S X ----
    for (int it = 0; it < NS_ITERS; ++it) {
        f32x4 acc[4];
#pragma unroll
        for (int c = 0; c < 4; ++c) { acc[c][0] = 0.f; acc[c][1] = 0.f; acc[c][2] = 0.f; acc[c][3] = 0.f; }
        mm_acc(B0, B2, acc, tr, tcb, l15, l4);      // T = S_hi X
        wb_hi_neg(B3, acc, tr, tcb, l15, l4);       // B3 = -T (no readers of B3 now)
        __syncthreads();
        f32x4 a2[4];
#pragma unroll
        for (int c = 0; c < 4; ++c)
#pragma unroll
            for (int j = 0; j < 4; ++j)
                a2[c][j] = 2.0f * bfu(B2[foidx(tr * 16 + l4 * 4 + j, (tcb + c) * 16 + l15)]);
        mm_acc(B2, B3, a2, tr, tcb, l15, l4);       // a2 = 2X - X^T T
        __syncthreads();                            // all reads of B2 done
        wb_hi(B2, a2, tr, tcb, l15, l4);
        __syncthreads();
    }

    // ---- symmetrize X ----
    for (int idx = tid; idx < 16384; idx += 1024) {
        const int r = idx >> 7, c = idx & 127;
        if (r <= c) {
            const int f1 = foidx(r, c), f2 = foidx(c, r);
            const unsigned short v = f2bf(0.5f * (bfu(B2[f1]) + bfu(B2[f2])));
            B2[f1] = v; B2[f2] = v;
        }
    }
    __syncthreads();

    // ---- refinement: T = (S_hi+S_lo) X (f32), E = 2I - T, W = X^T E ----
    {
        f32x4 acc[4];
#pragma unroll
        for (int c = 0; c < 4; ++c) { acc[c][0] = 0.f; acc[c][1] = 0.f; acc[c][2] = 0.f; acc[c][3] = 0.f; }
        mm_acc(B0, B2, acc, tr, tcb, l15, l4);
        mm_acc(B1, B2, acc, tr, tcb, l15, l4);
        __syncthreads();                            // reads of B1 done
        wb_split(B3, B1, acc, tr, tcb, l15, l4);    // T -> B3(hi), B1(lo)
        __syncthreads();
    }
    for (int idx = tid; idx < 16384; idx += 1024) { // E = 2I - T, in place
        const int r = idx >> 7, c = idx & 127;
        const int f = foidx(r, c);
        const float e = ((r == c) ? 2.0f : 0.0f) - (bfu(B3[f]) + bfu(B1[f]));
        const unsigned short hi = f2bf(e);
        B3[f] = hi; B1[f] = f2bf(e - bfu(hi));
    }
    __syncthreads();
    {
        f32x4 acc[4];
#pragma unroll
        for (int c = 0; c < 4; ++c) { acc[c][0] = 0.f; acc[c][1] = 0.f; acc[c][2] = 0.f; acc[c][3] = 0.f; }
        mm_acc(B2, B3, acc, tr, tcb, l15, l4);      // X^T E_hi
        mm_acc(B2, B1, acc, tr, tcb, l15, l4);      // X^T E_lo
        __syncthreads();
        wb_split(B0, B1, acc, tr, tcb, l15, l4);    // W -> B0(hi), B1(lo)
        __syncthreads();
    }

    // ---- symmetrize W (split) ----
    for (int idx = tid; idx < 16384; idx += 1024) {
        const int r = idx >> 7, c = idx & 127;
        if (r <= c) {
            const int f1 = foidx(r, c), f2 = foidx(c, r);
            const float v = 0.5f * ((bfu(B0[f1]) + bfu(B1[f1])) + (bfu(B0[f2]) + bfu(B1[f2])));
            const unsigned short hi = f2bf(v);
            const unsigned short lo = f2bf(v - bfu(hi));
            B0[f1] = hi; B0[f2] = hi; B1[f1] = lo; B1[f2] = lo;
        }
    }
    __syncthreads();

    // ---- emit wsB = W_hi; build M = I - W -> B2,B3; series orders 1,2 ----
    float tsum = 0.0f;
    for (int i = tid; i < 2048; i += 1024)
        reinterpret_cast<uint4*>(wsB)[i] = reinterpret_cast<const uint4*>(B0)[i];
    for (int idx = tid; idx < 16384; idx += 1024) {
        const int r = idx >> 7, c = idx & 127;
        const int f = foidx(r, c);
        const unsigned short mb = f2bf(((r == c) ? 1.0f : 0.0f) - (bfu(B0[f]) + bfu(B1[f])));
        B2[f] = mb; B3[f] = mb;
        const float mf = bfu(mb);
        tsum += 0.5f * mf * mf + ((r == c) ? mf : 0.0f);   // tr(M^2)/2 + tr(M)
    }
    __syncthreads();

    // ---- series: P_j = M^j, j=2..12; orders 2j-1, 2j via Frobenius dots ----
    for (int j = 2; j <= 12; ++j) {
        const float codd = 1.0f / (float)(2 * j - 1);
        const float cevn = 1.0f / (float)(2 * j);
        f32x4 acc[4];
#pragma unroll
        for (int c = 0; c < 4; ++c) { acc[c][0] = 0.f; acc[c][1] = 0.f; acc[c][2] = 0.f; acc[c][3] = 0.f; }
        mm_acc(B2, B3, acc, tr, tcb, l15, l4);      // M^T P_{j-1} = M^j
        __syncthreads();                            // reads of B3 done
#pragma unroll
        for (int c = 0; c < 4; ++c)
#pragma unroll
            for (int j4 = 0; j4 < 4; ++j4) {
                const int f = foidx(tr * 16 + l4 * 4 + j4, (tcb + c) * 16 + l15);
                const float old = bfu(B3[f]);       // P_{j-1}
                const float x = acc[c][j4];         // P_j (f32)
                B3[f] = f2bf(x);
                tsum += x * old * codd + x * x * cevn;
            }
        __syncthreads();
    }

    // ---- reduce tsum over 1024 threads ----
    {
        float s = tsum;
#pragma unroll
        for (int off = 1; off < 64; off <<= 1) s += __shfl_xor(s, off, 64);
        if (lane == 0) sred[w] = s;
    }
    __syncthreads();
    if (tid == 0) {
        float tot = 0.f;
        for (int i = 0; i < 16; ++i) tot += sred[i];
        wsScal[0] = 0.5f * ((float)DIM * LOG_2PI + tot);
    }
}

// ---------------------------------------------------------------------------
// Main kernel: persistent blocks, 64-row tiles (dot-form):
//   Y = (X_tile - mu)_bf16 @ W ;  quad[n] = sum_e Y[n][e]*diff[n][e]
//   out = 0.5*quad + log_den
// ---------------------------------------------------------------------------
__global__ __launch_bounds__(256) void gm_main(
    const float* __restrict__ X, const float* __restrict__ mu,
    const __hip_bfloat16* __restrict__ wsB, const float* __restrict__ wsScal,
    float* __restrict__ out, int ntiles)
{
    __shared__ __hip_bfloat16 sB[16 * 1024];  // 32KB, fragment-ordered W
    __shared__ unsigned short sA[64 * 128];   // 16KB, swizzled bf16 diff tile
    __shared__ float s_mu[DIM];

    const int tid  = threadIdx.x;
    const int lane = tid & 63;
    const int wave = tid >> 6;
    const int l15  = lane & 15;
    const int l4   = lane >> 4;

    {   // stage W (tile-invariant) and mu once
        const float4* bg = reinterpret_cast<const float4*>(wsB);
        float4* bs = reinterpret_cast<float4*>(sB);
#pragma unroll
        for (int i = 0; i < 8; ++i) bs[tid + i * 256] = bg[tid + i * 256];
        if (tid < DIM) s_mu[tid] = mu[tid];
    }
    const float logden = wsScal[0];
    __syncthreads();

    for (int t = blockIdx.x; t < ntiles; t += gridDim.x) {
        // ---- stage 64x128 diff tile -> bf16, XOR-swizzled ----
        const float4* xg = reinterpret_cast<const float4*>(X + (size_t)t * (64 * DIM));
#pragma unroll
        for (int i = 0; i < 8; ++i) {
            const int idx = tid + i * 256;
            const int r  = idx >> 5;
            const int c4 = idx & 31;
            float4 v = xg[idx];
            v.x -= s_mu[c4 * 4 + 0];
            v.y -= s_mu[c4 * 4 + 1];
            v.z -= s_mu[c4 * 4 + 2];
            v.w -= s_mu[c4 * 4 + 3];
            ushort4 b;
            b.x = f2bf(v.x); b.y = f2bf(v.y); b.z = f2bf(v.z); b.w = f2bf(v.w);
            char* p = (char*)sA + r * 256 + ((((c4 >> 1) ^ (r & 7)) << 4) | ((c4 & 1) << 3));
            *reinterpret_cast<ushort4*>(p) = b;
        }
        __syncthreads();

        // ---- MFMA: Y = diff @ W ----
        f32x4 acc[8];
#pragma unroll
        for (int c = 0; c < 8; ++c) { acc[c][0] = 0.f; acc[c][1] = 0.f; acc[c][2] = 0.f; acc[c][3] = 0.f; }

        const int arow = wave * 16 + l15;
        const char* aBase = (const char*)sA + arow * 256;
#pragma unroll
        for (int kk = 0; kk < 4; ++kk) {
            const int kchunk = kk * 4 + l4;
            bf16x8 af = *reinterpret_cast<const bf16x8*>(aBase + ((kchunk ^ (arow & 7)) << 4));
            const __hip_bfloat16* bbase = sB + kchunk * 1024 + l15 * 8;
#pragma unroll
            for (int c = 0; c < 8; ++c) {
                bf16x8 bf = *reinterpret_cast<const bf16x8*>(bbase + c * 128);
                acc[c] = __builtin_amdgcn_mfma_f32_16x16x32_bf16(af, bf, acc[c], 0, 0, 0);
            }
        }

        // ---- quad = rowdot(Y, diff): re-read own diff slices from sA ----
        float q0 = 0.f, q1 = 0.f, q2 = 0.f, q3 = 0.f;
#pragma unroll
        for (int c = 0; c < 8; ++c) {
            const int d = c * 16 + l15;
#pragma unroll
            for (int j = 0; j < 4; ++j) {
                const int r = wave * 16 + l4 * 4 + j;
                const int byt = r * 256 +
                    ((((d >> 3) ^ (r & 7)) << 4) | (((d >> 2) & 1) << 3) | ((d & 3) << 1));
                const unsigned short u = *reinterpret_cast<const unsigned short*>((const char*)sA + byt);
                const float df = __uint_as_float((unsigned int)u << 16);
                if (j == 0) q0 += acc[c][0] * df;
                else if (j == 1) q1 += acc[c][1] * df;
                else if (j == 2) q2 += acc[c][2] * df;
                else q3 += acc[c][3] * df;
            }
        }
#pragma unroll
        for (int off = 1; off < 16; off <<= 1) {
            q0 += __shfl_xor(q0, off, 64);
            q1 += __shfl_xor(q1, off, 64);
            q2 += __shfl_xor(q2, off, 64);
            q3 += __shfl_xor(q3, off, 64);
        }
        if (l15 == 0) {
            float4 o;
            o.x = 0.5f * q0 + logden;
            o.y = 0.5f * q1 + logden;
            o.z = 0.5f * q2 + logden;
            o.w = 0.5f * q3 + logden;
            *reinterpret_cast<float4*>(out + (size_t)t * 64 + wave * 16 + l4 * 4) = o;
        }
        __syncthreads();
    }
}

extern "C" void kernel_launch(void* const* d_in, const int* in_sizes, int n_in,
                              void* d_out, int out_size, void* d_ws, size_t ws_size,
                              hipStream_t stream) {
    const float* X     = (const float*)d_in[0];
    const float* mu    = (const float*)d_in[1];
    const float* sigma = (const float*)d_in[2];
    const float* eps   = (const float*)d_in[3];
    float* out = (float*)d_out;

    unsigned short* wsB = (unsigned short*)d_ws;
    float* wsScal = (float*)((char*)d_ws + 32768);

    const int N = in_sizes[0] / DIM;
    const int ntiles = N / 64;

    hipLaunchKernelGGL(gm_setup, dim3(1), dim3(1024), 0, stream, sigma, eps, wsB, wsScal);

    const int grid = ntiles < 768 ? ntiles : 768;
    hipLaunchKernelGGL(gm_main, dim3(grid), dim3(256), 0, stream,
                       X, mu, (const __hip_bfloat16*)wsB, wsScal, out, ntiles);
}

// Round 7
// 156.992 us; speedup vs baseline: 3.0603x; 1.0759x over previous
//
#include <hip/hip_runtime.h>
#include <hip/hip_bf16.h>

typedef __bf16 bf16x8 __attribute__((ext_vector_type(8)));
typedef float f32x4 __attribute__((ext_vector_type(4)));

#define DIM 128
#define LOG_2PI 1.8378770664093453f
#define NS_ITERS 9

__device__ __forceinline__ unsigned short f2bf(float f) {
    unsigned int u = __float_as_uint(f);
    u += 0x7FFFu + ((u >> 16) & 1u);
    return (unsigned short)(u >> 16);
}
__device__ __forceinline__ float bfu(unsigned short u) {
    return __uint_as_float((unsigned int)u << 16);
}
// fragment-order index: FO[(r>>3)*1024 + c*8 + (r&7)] = M[r][c]
__device__ __forceinline__ int foidx(int r, int c) {
    return ((r >> 3) << 10) + (c << 3) + (r & 7);
}

// acc += P^T * Q  (P,Q bf16 fragment order; conflict-free ds_read_b128)
__device__ __forceinline__ void mm_acc(const unsigned short* __restrict__ Ps,
                                       const unsigned short* __restrict__ Qs,
                                       f32x4* acc, int tr, int tcb, int l15, int l4)
{
#pragma unroll
    for (int kk = 0; kk < 4; ++kk) {
        const int kc = kk * 4 + l4;
        const bf16x8 a = *reinterpret_cast<const bf16x8*>(Ps + (kc << 10) + ((tr * 16 + l15) << 3));
#pragma unroll
        for (int c = 0; c < 4; ++c) {
            const bf16x8 b = *reinterpret_cast<const bf16x8*>(Qs + (kc << 10) + (((tcb + c) * 16 + l15) << 3));
            acc[c] = __builtin_amdgcn_mfma_f32_16x16x32_bf16(a, b, acc[c], 0, 0, 0);
        }
    }
}

// packed writeback: rows tr*16+l4*4+j (j=0..3) are 4 contiguous 8-aligned
// shorts in fragment order -> one ushort4 (b64) store per output column tile
__device__ __forceinline__ void wb_vec(unsigned short* __restrict__ C, const f32x4* acc,
                                       int tr, int tcb, int l15, int l4, float sgn)
{
    const int r0 = tr * 16 + l4 * 4;
#pragma unroll
    for (int c = 0; c < 4; ++c) {
        ushort4 p;
        p.x = f2bf(sgn * acc[c][0]); p.y = f2bf(sgn * acc[c][1]);
        p.z = f2bf(sgn * acc[c][2]); p.w = f2bf(sgn * acc[c][3]);
        *reinterpret_cast<ushort4*>(&C[foidx(r0, (tcb + c) * 16 + l15)]) = p;
    }
}

__device__ __forceinline__ void wb_split_vec(unsigned short* __restrict__ Chi,
                                             unsigned short* __restrict__ Clo,
                                             const f32x4* acc, int tr, int tcb, int l15, int l4)
{
    const int r0 = tr * 16 + l4 * 4;
#pragma unroll
    for (int c = 0; c < 4; ++c) {
        ushort4 ph, pl;
        const int f = foidx(r0, (tcb + c) * 16 + l15);
#pragma unroll
        for (int j = 0; j < 4; ++j) {
            const float v = acc[c][j];
            const unsigned short hi = f2bf(v);
            const unsigned short lo = f2bf(v - bfu(hi));
            ((unsigned short*)&ph)[j] = hi;
            ((unsigned short*)&pl)[j] = lo;
        }
        *reinterpret_cast<ushort4*>(&Chi[f]) = ph;
        *reinterpret_cast<ushort4*>(&Clo[f]) = pl;
    }
}

// ---------------------------------------------------------------------------
// Setup (1 block, 1024 threads = 16 waves, MFMA + vectorized LDS):
//   S = sigma+eps split bf16 hi/lo (B0,B1), fragment order
//   Newton-Schulz X <- 2X - X^T(S X), X0 = I/gershgorin(S), 9 iters (B2)
//   split refinement W = X^T(2I - S X) -> B0(hi),B1(lo); wsB = W_hi
//   M = I - W -> B2,B3; logdet = sum_k tr(M^k)/k, k=1..24, Frobenius trick
//   wsScal[0] = 0.5*(D*log(2pi) + logdet)
// Fragment-space vector v (uint4 = 8 shorts): c = v&127, rows (v>>7)*8..+7
// ---------------------------------------------------------------------------
__global__ __launch_bounds__(1024) void gm_setup(
    const float* __restrict__ sigma, const float* __restrict__ eps,
    unsigned short* __restrict__ wsB, float* __restrict__ wsScal)
{
    __shared__ __align__(16) unsigned short B0[16384];  // S_hi -> W_hi
    __shared__ __align__(16) unsigned short B1[16384];  // S_lo -> T/E_lo -> W_lo
    __shared__ __align__(16) unsigned short B2[16384];  // X -> M
    __shared__ __align__(16) unsigned short B3[16384];  // -T / E_hi -> P_j
    __shared__ float sred[DIM];
    __shared__ float sscal[1];

    const int tid  = threadIdx.x;
    const int lane = tid & 63;
    const int w    = tid >> 6;
    const int l15  = lane & 15;
    const int l4   = lane >> 4;
    const int tr   = w >> 1;          // output tile-row 0..7
    const int tcb  = (w & 1) * 4;     // output tile-col base 0 or 4
    const int r0   = tr * 16 + l4 * 4;

    // ---- load S = sigma + eps, split hi/lo, fragment order (vectorized) ----
#pragma unroll
    for (int h = 0; h < 2; ++h) {
        const int v = tid + h * 1024;          // vector index 0..2047
        const int c = v & 127, rb = v >> 7;    // 8 rows rb*8..rb*8+7, column c
        ushort4 h0, h1, l0, l1;
#pragma unroll
        for (int j = 0; j < 8; ++j) {
            const int gi = (rb * 8 + j) * DIM + c;   // lane-consecutive c -> coalesced
            const float s = sigma[gi] + eps[gi];
            const unsigned short hi = f2bf(s);
            const unsigned short lo = f2bf(s - bfu(hi));
            if (j < 4) { ((unsigned short*)&h0)[j] = hi; ((unsigned short*)&l0)[j] = lo; }
            else       { ((unsigned short*)&h1)[j-4] = hi; ((unsigned short*)&l1)[j-4] = lo; }
        }
        const int f = v * 8;
        *reinterpret_cast<ushort4*>(&B0[f])     = h0;
        *reinterpret_cast<ushort4*>(&B0[f + 4]) = h1;
        *reinterpret_cast<ushort4*>(&B1[f])     = l0;
        *reinterpret_cast<ushort4*>(&B1[f + 4]) = l1;
    }
    __syncthreads();

    // ---- Gershgorin bound b >= lambda_max(S);  x0 = 1/b ----
    if (tid < DIM) {
        const int base = ((tid >> 3) << 10) + (tid & 7);
        float s = 0.f;
        for (int c = 0; c < DIM; ++c) s += fabsf(bfu(B0[base + (c << 3)]));
        sred[tid] = s;
    }
    __syncthreads();
    if (tid < 64) {
        float m = fmaxf(sred[tid], sred[tid + 64]);
#pragma unroll
        for (int off = 32; off; off >>= 1) m = fmaxf(m, __shfl_xor(m, off, 64));
        if (tid == 0) sscal[0] = 1.0f / (m * 1.0078125f);
    }
    __syncthreads();
    const float x0 = sscal[0];
    const unsigned short x0b = f2bf(x0);

    // ---- X0 = x0 * I (vectorized) ----
#pragma unroll
    for (int h = 0; h < 2; ++h) {
        const int v = tid + h * 1024;
        const int c = v & 127, rb = v >> 7;
        ushort4 z0 = {0, 0, 0, 0}, z1 = {0, 0, 0, 0};
        const int dj = c - rb * 8;               // diagonal at row-offset dj
        if (dj >= 0 && dj < 4) ((unsigned short*)&z0)[dj] = x0b;
        if (dj >= 4 && dj < 8) ((unsigned short*)&z1)[dj - 4] = x0b;
        const int f = v * 8;
        *reinterpret_cast<ushort4*>(&B2[f])     = z0;
        *reinterpret_cast<ushort4*>(&B2[f + 4]) = z1;
    }
    __syncthreads();

    // ---- Newton-Schulz: X <- 2X + X^T(-T), T = S X ----
    for (int it = 0; it < NS_ITERS; ++it) {
        f32x4 acc[4];
#pragma unroll
        for (int c = 0; c < 4; ++c) { acc[c][0] = 0.f; acc[c][1] = 0.f; acc[c][2] = 0.f; acc[c][3] = 0.f; }
        mm_acc(B0, B2, acc, tr, tcb, l15, l4);      // T = S_hi X
        wb_vec(B3, acc, tr, tcb, l15, l4, -1.0f);   // B3 = -T
        __syncthreads();
        f32x4 a2[4];
#pragma unroll
        for (int c = 0; c < 4; ++c) {
            const ushort4 x4 = *reinterpret_cast<const ushort4*>(&B2[foidx(r0, (tcb + c) * 16 + l15)]);
            a2[c][0] = 2.0f * bfu(x4.x); a2[c][1] = 2.0f * bfu(x4.y);
            a2[c][2] = 2.0f * bfu(x4.z); a2[c][3] = 2.0f * bfu(x4.w);
        }
        mm_acc(B2, B3, a2, tr, tcb, l15, l4);       // a2 = 2X - X^T T
        __syncthreads();                            // all reads of B2 done
        wb_vec(B2, a2, tr, tcb, l15, l4, 1.0f);
        __syncthreads();
    }

    // ---- refinement: T = (S_hi+S_lo) X (f32), E = 2I - T, W = X^T E ----
    {
        f32x4 acc[4];
#pragma unroll
        for (int c = 0; c < 4; ++c) { acc[c][0] = 0.f; acc[c][1] = 0.f; acc[c][2] = 0.f; acc[c][3] = 0.f; }
        mm_acc(B0, B2, acc, tr, tcb, l15, l4);
        mm_acc(B1, B2, acc, tr, tcb, l15, l4);
        __syncthreads();                            // reads of B1 done
        wb_split_vec(B3, B1, acc, tr, tcb, l15, l4);// T -> B3(hi), B1(lo)
        __syncthreads();
    }
#pragma unroll
    for (int h = 0; h < 2; ++h) {                   // E = 2I - T, in place (vec)
        const int v = tid + h * 1024;
        const int c = v & 127, rb = v >> 7;
        const int f = v * 8;
        ushort4 th[2], tl[2];
        th[0] = *reinterpret_cast<const ushort4*>(&B3[f]);
        th[1] = *reinterpret_cast<const ushort4*>(&B3[f + 4]);
        tl[0] = *reinterpret_cast<const ushort4*>(&B1[f]);
        tl[1] = *reinterpret_cast<const ushort4*>(&B1[f + 4]);
#pragma unroll
        for (int q = 0; q < 2; ++q) {
            ushort4 eh, el;
#pragma unroll
            for (int j = 0; j < 4; ++j) {
                const int r = rb * 8 + q * 4 + j;
                const float t = bfu(((const unsigned short*)&th[q])[j]) + bfu(((const unsigned short*)&tl[q])[j]);
                const float e = ((r == c) ? 2.0f : 0.0f) - t;
                const unsigned short hi = f2bf(e);
                ((unsigned short*)&eh)[j] = hi;
                ((unsigned short*)&el)[j] = f2bf(e - bfu(hi));
            }
            *reinterpret_cast<ushort4*>(&B3[f + q * 4]) = eh;
            *reinterpret_cast<ushort4*>(&B1[f + q * 4]) = el;
        }
    }
    __syncthreads();
    {
        f32x4 acc[4];
#pragma unroll
        for (int c = 0; c < 4; ++c) { acc[c][0] = 0.f; acc[c][1] = 0.f; acc[c][2] = 0.f; acc[c][3] = 0.f; }
        mm_acc(B2, B3, acc, tr, tcb, l15, l4);      // X^T E_hi
        mm_acc(B2, B1, acc, tr, tcb, l15, l4);      // X^T E_lo
        __syncthreads();                            // reads of B1 done
        wb_split_vec(B0, B1, acc, tr, tcb, l15, l4);// W -> B0(hi), B1(lo)
        __syncthreads();
    }

    // ---- emit wsB = W_hi; build M = I - W -> B2,B3; series orders 1,2 ----
    float tsum = 0.0f;
    for (int i = tid; i < 2048; i += 1024)
        reinterpret_cast<uint4*>(wsB)[i] = reinterpret_cast<const uint4*>(B0)[i];
#pragma unroll
    for (int h = 0; h < 2; ++h) {
        const int v = tid + h * 1024;
        const int c = v & 127, rb = v >> 7;
        const int f = v * 8;
#pragma unroll
        for (int q = 0; q < 2; ++q) {
            const ushort4 wh = *reinterpret_cast<const ushort4*>(&B0[f + q * 4]);
            const ushort4 wl = *reinterpret_cast<const ushort4*>(&B1[f + q * 4]);
            ushort4 mv;
#pragma unroll
            for (int j = 0; j < 4; ++j) {
                const int r = rb * 8 + q * 4 + j;
                const float wval = bfu(((const unsigned short*)&wh)[j]) + bfu(((const unsigned short*)&wl)[j]);
                const unsigned short mb = f2bf(((r == c) ? 1.0f : 0.0f) - wval);
                ((unsigned short*)&mv)[j] = mb;
                const float mf = bfu(mb);
                tsum += 0.5f * mf * mf + ((r == c) ? mf : 0.0f);   // tr(M^2)/2 + tr(M)
            }
            *reinterpret_cast<ushort4*>(&B2[f + q * 4]) = mv;
            *reinterpret_cast<ushort4*>(&B3[f + q * 4]) = mv;
        }
    }
    __syncthreads();

    // ---- series: P_j = M^j, j=2..12; orders 2j-1, 2j via Frobenius dots ----
    for (int j = 2; j <= 12; ++j) {
        const float codd = 1.0f / (float)(2 * j - 1);
        const float cevn = 1.0f / (float)(2 * j);
        f32x4 acc[4];
#pragma unroll
        for (int c = 0; c < 4; ++c) { acc[c][0] = 0.f; acc[c][1] = 0.f; acc[c][2] = 0.f; acc[c][3] = 0.f; }
        mm_acc(B2, B3, acc, tr, tcb, l15, l4);      // M^T P_{j-1} = M^j
        __syncthreads();                            // reads of B3 done
#pragma unroll
        for (int c = 0; c < 4; ++c) {
            const int f = foidx(r0, (tcb + c) * 16 + l15);
            const ushort4 old4 = *reinterpret_cast<const ushort4*>(&B3[f]);
            ushort4 nw;
#pragma unroll
            for (int j4 = 0; j4 < 4; ++j4) {
                const float x = acc[c][j4];
                ((unsigned short*)&nw)[j4] = f2bf(x);
                tsum += x * bfu(((const unsigned short*)&old4)[j4]) * codd + x * x * cevn;
            }
            *reinterpret_cast<ushort4*>(&B3[f]) = nw;
        }
        __syncthreads();
    }

    // ---- reduce tsum over 1024 threads ----
    {
        float s = tsum;
#pragma unroll
        for (int off = 1; off < 64; off <<= 1) s += __shfl_xor(s, off, 64);
        if (lane == 0) sred[w] = s;
    }
    __syncthreads();
    if (tid == 0) {
        float tot = 0.f;
        for (int i = 0; i < 16; ++i) tot += sred[i];
        wsScal[0] = 0.5f * ((float)DIM * LOG_2PI + tot);
    }
}

// ---------------------------------------------------------------------------
// Main kernel: persistent blocks, 64-row tiles (dot-form). UNCHANGED.
//   Y = (X_tile - mu)_bf16 @ W ;  quad[n] = sum_e Y[n][e]*diff[n][e]
//   out = 0.5*quad + log_den
// ---------------------------------------------------------------------------
__global__ __launch_bounds__(256) void gm_main(
    const float* __restrict__ X, const float* __restrict__ mu,
    const __hip_bfloat16* __restrict__ wsB, const float* __restrict__ wsScal,
    float* __restrict__ out, int ntiles)
{
    __shared__ __hip_bfloat16 sB[16 * 1024];  // 32KB, fragment-ordered W
    __shared__ unsigned short sA[64 * 128];   // 16KB, swizzled bf16 diff tile
    __shared__ float s_mu[DIM];

    const int tid  = threadIdx.x;
    const int lane = tid & 63;
    const int wave = tid >> 6;
    const int l15  = lane & 15;
    const int l4   = lane >> 4;

    {   // stage W (tile-invariant) and mu once
        const float4* bg = reinterpret_cast<const float4*>(wsB);
        float4* bs = reinterpret_cast<float4*>(sB);
#pragma unroll
        for (int i = 0; i < 8; ++i) bs[tid + i * 256] = bg[tid + i * 256];
        if (tid < DIM) s_mu[tid] = mu[tid];
    }
    const float logden = wsScal[0];
    __syncthreads();

    for (int t = blockIdx.x; t < ntiles; t += gridDim.x) {
        // ---- stage 64x128 diff tile -> bf16, XOR-swizzled ----
        const float4* xg = reinterpret_cast<const float4*>(X + (size_t)t * (64 * DIM));
#pragma unroll
        for (int i = 0; i < 8; ++i) {
            const int idx = tid + i * 256;
            const int r  = idx >> 5;
            const int c4 = idx & 31;
            float4 v = xg[idx];
            v.x -= s_mu[c4 * 4 + 0];
            v.y -= s_mu[c4 * 4 + 1];
            v.z -= s_mu[c4 * 4 + 2];
            v.w -= s_mu[c4 * 4 + 3];
            ushort4 b;
            b.x = f2bf(v.x); b.y = f2bf(v.y); b.z = f2bf(v.z); b.w = f2bf(v.w);
            char* p = (char*)sA + r * 256 + ((((c4 >> 1) ^ (r & 7)) << 4) | ((c4 & 1) << 3));
            *reinterpret_cast<ushort4*>(p) = b;
        }
        __syncthreads();

        // ---- MFMA: Y = diff @ W ----
        f32x4 acc[8];
#pragma unroll
        for (int c = 0; c < 8; ++c) { acc[c][0] = 0.f; acc[c][1] = 0.f; acc[c][2] = 0.f; acc[c][3] = 0.f; }

        const int arow = wave * 16 + l15;
        const char* aBase = (const char*)sA + arow * 256;
#pragma unroll
        for (int kk = 0; kk < 4; ++kk) {
            const int kchunk = kk * 4 + l4;
            bf16x8 af = *reinterpret_cast<const bf16x8*>(aBase + ((kchunk ^ (arow & 7)) << 4));
            const __hip_bfloat16* bbase = sB + kchunk * 1024 + l15 * 8;
#pragma unroll
            for (int c = 0; c < 8; ++c) {
                bf16x8 bf = *reinterpret_cast<const bf16x8*>(bbase + c * 128);
                acc[c] = __builtin_amdgcn_mfma_f32_16x16x32_bf16(af, bf, acc[c], 0, 0, 0);
            }
        }

        // ---- quad = rowdot(Y, diff): re-read own diff slices from sA ----
        float q0 = 0.f, q1 = 0.f, q2 = 0.f, q3 = 0.f;
#pragma unroll
        for (int c = 0; c < 8; ++c) {
            const int d = c * 16 + l15;
#pragma unroll
            for (int j = 0; j < 4; ++j) {
                const int r = wave * 16 + l4 * 4 + j;
                const int byt = r * 256 +
                    ((((d >> 3) ^ (r & 7)) << 4) | (((d >> 2) & 1) << 3) | ((d & 3) << 1));
                const unsigned short u = *reinterpret_cast<const unsigned short*>((const char*)sA + byt);
                const float df = __uint_as_float((unsigned int)u << 16);
                if (j == 0) q0 += acc[c][0] * df;
                else if (j == 1) q1 += acc[c][1] * df;
                else if (j == 2) q2 += acc[c][2] * df;
                else q3 += acc[c][3] * df;
            }
        }
#pragma unroll
        for (int off = 1; off < 16; off <<= 1) {
            q0 += __shfl_xor(q0, off, 64);
            q1 += __shfl_xor(q1, off, 64);
            q2 += __shfl_xor(q2, off, 64);
            q3 += __shfl_xor(q3, off, 64);
        }
        if (l15 == 0) {
            float4 o;
            o.x = 0.5f * q0 + logden;
            o.y = 0.5f * q1 + logden;
            o.z = 0.5f * q2 + logden;
            o.w = 0.5f * q3 + logden;
            *reinterpret_cast<float4*>(out + (size_t)t * 64 + wave * 16 + l4 * 4) = o;
        }
        __syncthreads();
    }
}

extern "C" void kernel_launch(void* const* d_in, const int* in_sizes, int n_in,
                              void* d_out, int out_size, void* d_ws, size_t ws_size,
                              hipStream_t stream) {
    const float* X     = (const float*)d_in[0];
    const float* mu    = (const float*)d_in[1];
    const float* sigma = (const float*)d_in[2];
    const float* eps   = (const float*)d_in[3];
    float* out = (float*)d_out;

    unsigned short* wsB = (unsigned short*)d_ws;
    float* wsScal = (float*)((char*)d_ws + 32768);

    const int N = in_sizes[0] / DIM;
    const int ntiles = N / 64;

    hipLaunchKernelGGL(gm_setup, dim3(1), dim3(1024), 0, stream, sigma, eps, wsB, wsScal);

    const int grid = ntiles < 768 ? ntiles : 768;
    hipLaunchKernelGGL(gm_main, dim3(grid), dim3(256), 0, stream,
                       X, mu, (const __hip_bfloat16*)wsB, wsScal, out, ntiles);
}

// Round 8
// 135.000 us; speedup vs baseline: 3.5588x; 1.1629x over previous
//
#include <hip/hip_runtime.h>
#include <hip/hip_bf16.h>

typedef __bf16 bf16x8 __attribute__((ext_vector_type(8)));
typedef float f32x4 __attribute__((ext_vector_type(4)));

#define DIM 128
#define LOG_2PI 1.8378770664093453f
#define NS_ITERS 6   // even (X ends in B2); e0^(2^6) << bf16 floor

__device__ __forceinline__ unsigned short f2bf(float f) {
    unsigned int u = __float_as_uint(f);
    u += 0x7FFFu + ((u >> 16) & 1u);
    return (unsigned short)(u >> 16);
}
__device__ __forceinline__ float bfu(unsigned short u) {
    return __uint_as_float((unsigned int)u << 16);
}
// fragment-order index: FO[(r>>3)*1024 + c*8 + (r&7)] = M[r][c]
__device__ __forceinline__ int foidx(int r, int c) {
    return ((r >> 3) << 10) + (c << 3) + (r & 7);
}

// acc += P^T * Q  (P,Q bf16 fragment order; conflict-free ds_read_b128)
__device__ __forceinline__ void mm_acc(const unsigned short* __restrict__ Ps,
                                       const unsigned short* __restrict__ Qs,
                                       f32x4* acc, int tr, int tcb, int l15, int l4)
{
#pragma unroll
    for (int kk = 0; kk < 4; ++kk) {
        const int kc = kk * 4 + l4;
        const bf16x8 a = *reinterpret_cast<const bf16x8*>(Ps + (kc << 10) + ((tr * 16 + l15) << 3));
#pragma unroll
        for (int c = 0; c < 4; ++c) {
            const bf16x8 b = *reinterpret_cast<const bf16x8*>(Qs + (kc << 10) + (((tcb + c) * 16 + l15) << 3));
            acc[c] = __builtin_amdgcn_mfma_f32_16x16x32_bf16(a, b, acc[c], 0, 0, 0);
        }
    }
}

// packed writeback: rows r0..r0+3 are 4 contiguous 8-aligned shorts -> b64 store
__device__ __forceinline__ void wb_vec(unsigned short* __restrict__ C, const f32x4* acc,
                                       int r0, int tcb, int l15, float sgn)
{
#pragma unroll
    for (int c = 0; c < 4; ++c) {
        ushort4 p;
        p.x = f2bf(sgn * acc[c][0]); p.y = f2bf(sgn * acc[c][1]);
        p.z = f2bf(sgn * acc[c][2]); p.w = f2bf(sgn * acc[c][3]);
        *reinterpret_cast<ushort4*>(&C[foidx(r0, (tcb + c) * 16 + l15)]) = p;
    }
}

// ---------------------------------------------------------------------------
// Setup (1 block, 1024 threads = 16 waves, MFMA, 21 matmuls total):
//   S = sigma+eps split bf16 hi(B0)/lo(stashed in regs, B1 used as X ping-pong)
//   NS: X <- 2X - X^T(S_hi X), X0 = I/gershgorin, 6 iters, 2 barriers/iter
//   refinement (split S): T = S X, E = 2I - T (regs), W = X^T E
//   wsB = W_hi (global, from regs); M = I - W -> B2,B3 (f32 traces 1,2)
//   series P_j = M^j, j=2..6: orders 3..12 via Frobenius dots (old P in regs)
//   wsScal[0] = 0.5*(D*log(2pi) + logdet)
// ---------------------------------------------------------------------------
__global__ __launch_bounds__(1024) void gm_setup(
    const float* __restrict__ sigma, const float* __restrict__ eps,
    unsigned short* __restrict__ wsB, float* __restrict__ wsScal)
{
    __shared__ __align__(16) unsigned short B0[16384];  // S_hi
    __shared__ __align__(16) unsigned short B1[16384];  // X ping-pong / E_lo
    __shared__ __align__(16) unsigned short B2[16384];  // X ping-pong / M
    __shared__ __align__(16) unsigned short B3[16384];  // -T / E_hi / P_j
    __shared__ float sred[DIM];
    __shared__ float sscal[1];

    const int tid  = threadIdx.x;
    const int lane = tid & 63;
    const int w    = tid >> 6;
    const int l15  = lane & 15;
    const int l4   = lane >> 4;
    const int tr   = w >> 1;          // output tile-row 0..7
    const int tcb  = (w & 1) * 4;     // output tile-col base 0 or 4
    const int r0   = tr * 16 + l4 * 4;

    // ---- load S = sigma + eps; hi -> B0, lo -> stashed registers ----
    ushort4 slo_st[4];                // S_lo for this thread's 2 vectors (32B)
#pragma unroll
    for (int h = 0; h < 2; ++h) {
        const int v = tid + h * 1024;          // vector index 0..2047
        const int c = v & 127, rb = v >> 7;    // rows rb*8..rb*8+7, column c
        ushort4 h0, h1, l0, l1;
#pragma unroll
        for (int j = 0; j < 8; ++j) {
            const int gi = (rb * 8 + j) * DIM + c;
            const float s = sigma[gi] + eps[gi];
            const unsigned short hi = f2bf(s);
            const unsigned short lo = f2bf(s - bfu(hi));
            if (j < 4) { ((unsigned short*)&h0)[j] = hi; ((unsigned short*)&l0)[j] = lo; }
            else       { ((unsigned short*)&h1)[j-4] = hi; ((unsigned short*)&l1)[j-4] = lo; }
        }
        const int f = v * 8;
        *reinterpret_cast<ushort4*>(&B0[f])     = h0;
        *reinterpret_cast<ushort4*>(&B0[f + 4]) = h1;
        slo_st[h * 2]     = l0;
        slo_st[h * 2 + 1] = l1;
    }
    __syncthreads();

    // ---- Gershgorin via column sums (S symmetric): thread = column ----
    if (tid < DIM) {
        float s = 0.f;
#pragma unroll
        for (int rb = 0; rb < 16; ++rb) {
            const ushort4 a = *reinterpret_cast<const ushort4*>(&B0[rb * 1024 + tid * 8]);
            const ushort4 b = *reinterpret_cast<const ushort4*>(&B0[rb * 1024 + tid * 8 + 4]);
            s += fabsf(bfu(a.x)) + fabsf(bfu(a.y)) + fabsf(bfu(a.z)) + fabsf(bfu(a.w));
            s += fabsf(bfu(b.x)) + fabsf(bfu(b.y)) + fabsf(bfu(b.z)) + fabsf(bfu(b.w));
        }
        sred[tid] = s;
    }
    __syncthreads();
    if (tid < 64) {
        float m = fmaxf(sred[tid], sred[tid + 64]);
#pragma unroll
        for (int off = 32; off; off >>= 1) m = fmaxf(m, __shfl_xor(m, off, 64));
        if (tid == 0) sscal[0] = 1.0f / (m * 1.0078125f);
    }
    __syncthreads();
    const unsigned short x0b = f2bf(sscal[0]);

    // ---- X0 = x0 * I -> B2 ----
#pragma unroll
    for (int h = 0; h < 2; ++h) {
        const int v = tid + h * 1024;
        const int c = v & 127, rb = v >> 7;
        ushort4 z0 = {0, 0, 0, 0}, z1 = {0, 0, 0, 0};
        const int dj = c - rb * 8;
        if (dj >= 0 && dj < 4) ((unsigned short*)&z0)[dj] = x0b;
        if (dj >= 4 && dj < 8) ((unsigned short*)&z1)[dj - 4] = x0b;
        const int f = v * 8;
        *reinterpret_cast<ushort4*>(&B2[f])     = z0;
        *reinterpret_cast<ushort4*>(&B2[f + 4]) = z1;
    }
    __syncthreads();

    // ---- Newton-Schulz, ping-pong B2<->B1, 2 barriers/iter ----
    for (int it = 0; it < NS_ITERS; ++it) {
        unsigned short* Xc = (it & 1) ? B1 : B2;
        unsigned short* Xo = (it & 1) ? B2 : B1;
        f32x4 acc[4];
#pragma unroll
        for (int c = 0; c < 4; ++c) { acc[c][0] = 0.f; acc[c][1] = 0.f; acc[c][2] = 0.f; acc[c][3] = 0.f; }
        mm_acc(B0, Xc, acc, tr, tcb, l15, l4);      // T = S X
        wb_vec(B3, acc, r0, tcb, l15, -1.0f);       // B3 = -T (no live readers)
        __syncthreads();
        f32x4 a2[4];
#pragma unroll
        for (int c = 0; c < 4; ++c) {
            const ushort4 x4 = *reinterpret_cast<const ushort4*>(&Xc[foidx(r0, (tcb + c) * 16 + l15)]);
            a2[c][0] = 2.0f * bfu(x4.x); a2[c][1] = 2.0f * bfu(x4.y);
            a2[c][2] = 2.0f * bfu(x4.z); a2[c][3] = 2.0f * bfu(x4.w);
        }
        mm_acc(Xc, B3, a2, tr, tcb, l15, l4);       // a2 = 2X - X^T T
        wb_vec(Xo, a2, r0, tcb, l15, 1.0f);         // Xo unread -> safe pre-barrier
        __syncthreads();
    }
    // X final in B2 (NS_ITERS even)

    // ---- restore S_lo -> B1 from stashed regs ----
#pragma unroll
    for (int h = 0; h < 2; ++h) {
        const int f = (tid + h * 1024) * 8;
        *reinterpret_cast<ushort4*>(&B1[f])     = slo_st[h * 2];
        *reinterpret_cast<ushort4*>(&B1[f + 4]) = slo_st[h * 2 + 1];
    }
    __syncthreads();

    // ---- refinement: T = (S_hi+S_lo) X; E = 2I - T (regs, split) ----
    ushort4 elv[4];
    {
        f32x4 acc[4];
#pragma unroll
        for (int c = 0; c < 4; ++c) { acc[c][0] = 0.f; acc[c][1] = 0.f; acc[c][2] = 0.f; acc[c][3] = 0.f; }
        mm_acc(B0, B2, acc, tr, tcb, l15, l4);
        mm_acc(B1, B2, acc, tr, tcb, l15, l4);
#pragma unroll
        for (int c = 0; c < 4; ++c) {
            const int col = (tcb + c) * 16 + l15;
            ushort4 eh;
#pragma unroll
            for (int j = 0; j < 4; ++j) {
                const float e = ((r0 + j == col) ? 2.0f : 0.0f) - acc[c][j];
                const unsigned short hi = f2bf(e);
                ((unsigned short*)&eh)[j] = hi;
                ((unsigned short*)&elv[c])[j] = f2bf(e - bfu(hi));
            }
            *reinterpret_cast<ushort4*>(&B3[foidx(r0, col)]) = eh;  // B3 unread now
        }
        __syncthreads();                            // B1 mm-reads done, E_hi ready
    }
#pragma unroll
    for (int c = 0; c < 4; ++c)
        *reinterpret_cast<ushort4*>(&B1[foidx(r0, (tcb + c) * 16 + l15)]) = elv[c];
    __syncthreads();                                // E_lo ready

    // ---- W = X^T E (split); write W_hi->global; M = I - W -> B2,B3 ----
    float tsum = 0.0f;
    ushort4 pold[4];
    {
        f32x4 acc[4];
#pragma unroll
        for (int c = 0; c < 4; ++c) { acc[c][0] = 0.f; acc[c][1] = 0.f; acc[c][2] = 0.f; acc[c][3] = 0.f; }
        mm_acc(B2, B3, acc, tr, tcb, l15, l4);      // X^T E_hi
        mm_acc(B2, B1, acc, tr, tcb, l15, l4);      // X^T E_lo
        __syncthreads();                            // B2/B3 reads done
#pragma unroll
        for (int c = 0; c < 4; ++c) {
            const int col = (tcb + c) * 16 + l15;
            const int f = foidx(r0, col);
            ushort4 wh, mv;
#pragma unroll
            for (int j = 0; j < 4; ++j) {
                const float wv = acc[c][j];
                ((unsigned short*)&wh)[j] = f2bf(wv);
                const float mf = ((r0 + j == col) ? 1.0f : 0.0f) - wv;  // f32 M
                ((unsigned short*)&mv)[j] = f2bf(mf);
                tsum += 0.5f * mf * mf + ((r0 + j == col) ? mf : 0.0f); // tr(M)+tr(M^2)/2
            }
            *reinterpret_cast<ushort4*>(&wsB[f]) = wh;   // global W_hi
            *reinterpret_cast<ushort4*>(&B2[f]) = mv;
            *reinterpret_cast<ushort4*>(&B3[f]) = mv;
            pold[c] = mv;
        }
        __syncthreads();
    }

    // ---- series: P_j = M^j, j=2..6; orders 2j-1, 2j via Frobenius dots ----
    for (int j = 2; j <= 6; ++j) {
        const float codd = 1.0f / (float)(2 * j - 1);
        const float cevn = 1.0f / (float)(2 * j);
        f32x4 acc[4];
#pragma unroll
        for (int c = 0; c < 4; ++c) { acc[c][0] = 0.f; acc[c][1] = 0.f; acc[c][2] = 0.f; acc[c][3] = 0.f; }
        mm_acc(B2, B3, acc, tr, tcb, l15, l4);      // M^T P_{j-1}
        __syncthreads();                            // B3 reads done
#pragma unroll
        for (int c = 0; c < 4; ++c) {
            const int f = foidx(r0, (tcb + c) * 16 + l15);
            ushort4 nw;
#pragma unroll
            for (int j4 = 0; j4 < 4; ++j4) {
                const float x = acc[c][j4];
                ((unsigned short*)&nw)[j4] = f2bf(x);
                tsum += x * bfu(((const unsigned short*)&pold[c])[j4]) * codd + x * x * cevn;
            }
            *reinterpret_cast<ushort4*>(&B3[f]) = nw;
            pold[c] = nw;
        }
        __syncthreads();
    }

    // ---- reduce tsum over 1024 threads ----
    {
        float s = tsum;
#pragma unroll
        for (int off = 1; off < 64; off <<= 1) s += __shfl_xor(s, off, 64);
        if (lane == 0) sred[w] = s;
    }
    __syncthreads();
    if (tid == 0) {
        float tot = 0.f;
        for (int i = 0; i < 16; ++i) tot += sred[i];
        wsScal[0] = 0.5f * ((float)DIM * LOG_2PI + tot);
    }
}

// ---------------------------------------------------------------------------
// Main kernel: persistent blocks, 64-row tiles (dot-form). UNCHANGED.
//   Y = (X_tile - mu)_bf16 @ W ;  quad[n] = sum_e Y[n][e]*diff[n][e]
//   out = 0.5*quad + log_den
// ---------------------------------------------------------------------------
__global__ __launch_bounds__(256) void gm_main(
    const float* __restrict__ X, const float* __restrict__ mu,
    const __hip_bfloat16* __restrict__ wsB, const float* __restrict__ wsScal,
    float* __restrict__ out, int ntiles)
{
    __shared__ __hip_bfloat16 sB[16 * 1024];  // 32KB, fragment-ordered W
    __shared__ unsigned short sA[64 * 128];   // 16KB, swizzled bf16 diff tile
    __shared__ float s_mu[DIM];

    const int tid  = threadIdx.x;
    const int lane = tid & 63;
    const int wave = tid >> 6;
    const int l15  = lane & 15;
    const int l4   = lane >> 4;

    {   // stage W (tile-invariant) and mu once
        const float4* bg = reinterpret_cast<const float4*>(wsB);
        float4* bs = reinterpret_cast<float4*>(sB);
#pragma unroll
        for (int i = 0; i < 8; ++i) bs[tid + i * 256] = bg[tid + i * 256];
        if (tid < DIM) s_mu[tid] = mu[tid];
    }
    const float logden = wsScal[0];
    __syncthreads();

    for (int t = blockIdx.x; t < ntiles; t += gridDim.x) {
        // ---- stage 64x128 diff tile -> bf16, XOR-swizzled ----
        const float4* xg = reinterpret_cast<const float4*>(X + (size_t)t * (64 * DIM));
#pragma unroll
        for (int i = 0; i < 8; ++i) {
            const int idx = tid + i * 256;
            const int r  = idx >> 5;
            const int c4 = idx & 31;
            float4 v = xg[idx];
            v.x -= s_mu[c4 * 4 + 0];
            v.y -= s_mu[c4 * 4 + 1];
            v.z -= s_mu[c4 * 4 + 2];
            v.w -= s_mu[c4 * 4 + 3];
            ushort4 b;
            b.x = f2bf(v.x); b.y = f2bf(v.y); b.z = f2bf(v.z); b.w = f2bf(v.w);
            char* p = (char*)sA + r * 256 + ((((c4 >> 1) ^ (r & 7)) << 4) | ((c4 & 1) << 3));
            *reinterpret_cast<ushort4*>(p) = b;
        }
        __syncthreads();

        // ---- MFMA: Y = diff @ W ----
        f32x4 acc[8];
#pragma unroll
        for (int c = 0; c < 8; ++c) { acc[c][0] = 0.f; acc[c][1] = 0.f; acc[c][2] = 0.f; acc[c][3] = 0.f; }

        const int arow = wave * 16 + l15;
        const char* aBase = (const char*)sA + arow * 256;
#pragma unroll
        for (int kk = 0; kk < 4; ++kk) {
            const int kchunk = kk * 4 + l4;
            bf16x8 af = *reinterpret_cast<const bf16x8*>(aBase + ((kchunk ^ (arow & 7)) << 4));
            const __hip_bfloat16* bbase = sB + kchunk * 1024 + l15 * 8;
#pragma unroll
            for (int c = 0; c < 8; ++c) {
                bf16x8 bf = *reinterpret_cast<const bf16x8*>(bbase + c * 128);
                acc[c] = __builtin_amdgcn_mfma_f32_16x16x32_bf16(af, bf, acc[c], 0, 0, 0);
            }
        }

        // ---- quad = rowdot(Y, diff): re-read own diff slices from sA ----
        float q0 = 0.f, q1 = 0.f, q2 = 0.f, q3 = 0.f;
#pragma unroll
        for (int c = 0; c < 8; ++c) {
            const int d = c * 16 + l15;
#pragma unroll
            for (int j = 0; j < 4; ++j) {
                const int r = wave * 16 + l4 * 4 + j;
                const int byt = r * 256 +
                    ((((d >> 3) ^ (r & 7)) << 4) | (((d >> 2) & 1) << 3) | ((d & 3) << 1));
                const unsigned short u = *reinterpret_cast<const unsigned short*>((const char*)sA + byt);
                const float df = __uint_as_float((unsigned int)u << 16);
                if (j == 0) q0 += acc[c][0] * df;
                else if (j == 1) q1 += acc[c][1] * df;
                else if (j == 2) q2 += acc[c][2] * df;
                else q3 += acc[c][3] * df;
            }
        }
#pragma unroll
        for (int off = 1; off < 16; off <<= 1) {
            q0 += __shfl_xor(q0, off, 64);
            q1 += __shfl_xor(q1, off, 64);
            q2 += __shfl_xor(q2, off, 64);
            q3 += __shfl_xor(q3, off, 64);
        }
        if (l15 == 0) {
            float4 o;
            o.x = 0.5f * q0 + logden;
            o.y = 0.5f * q1 + logden;
            o.z = 0.5f * q2 + logden;
            o.w = 0.5f * q3 + logden;
            *reinterpret_cast<float4*>(out + (size_t)t * 64 + wave * 16 + l4 * 4) = o;
        }
        __syncthreads();
    }
}

extern "C" void kernel_launch(void* const* d_in, const int* in_sizes, int n_in,
                              void* d_out, int out_size, void* d_ws, size_t ws_size,
                              hipStream_t stream) {
    const float* X     = (const float*)d_in[0];
    const float* mu    = (const float*)d_in[1];
    const float* sigma = (const float*)d_in[2];
    const float* eps   = (const float*)d_in[3];
    float* out = (float*)d_out;

    unsigned short* wsB = (unsigned short*)d_ws;
    float* wsScal = (float*)((char*)d_ws + 32768);

    const int N = in_sizes[0] / DIM;
    const int ntiles = N / 64;

    hipLaunchKernelGGL(gm_setup, dim3(1), dim3(1024), 0, stream, sigma, eps, wsB, wsScal);

    const int grid = ntiles < 768 ? ntiles : 768;
    hipLaunchKernelGGL(gm_main, dim3(grid), dim3(256), 0, stream,
                       X, mu, (const __hip_bfloat16*)wsB, wsScal, out, ntiles);
}